// Round 10
// baseline (1181.706 us; speedup 1.0000x reference)
//
#include <hip/hip_runtime.h>
#include <cmath>
#include <cfloat>

#define B_   256
#define N_   100
#define D_   100
#define BN_  25600

typedef _Float16 f16;
typedef _Float16 f16x8 __attribute__((ext_vector_type(8)));
typedef float    f32x4 __attribute__((ext_vector_type(4)));

// node -> subnet id (partition), from _SUBNET_MAP (1-indexed in python)
__device__ const int d_node2k[100] = {
 0,0,0,0,0,0,0,0,0,
 1,1,1,1,1,1,
 2,2,2,2,2,2,2,2,
 3,3,3,3,3,3,3,
 4,4,4,
 5,5,5,5,
 6,6,6,6,6,6,6,6,6,6,6,6,6,
 0,0,0,0,0,0,0,0,
 1,1,1,1,1,1,1,1,
 2,2,2,2,2,2,2,
 3,3,3,3,3,
 4,4,
 5,5,5,5,5,5,5,5,5,
 6,6,6,6,6,6,6,6,6,6,6};

__device__ __forceinline__ double get_rho(int epoch){
    double t = 1.0 - (double)epoch / 600.0;
    return 0.8 + (1.0 - 0.8) * exp(-5.0 * t * t);
}

// ------------------------- misc small kernels -------------------------
__global__ void k_pos_embed(float* pose){
    int idx = blockIdx.x * blockDim.x + threadIdx.x;
    if (idx >= N_ * D_) return;
    int n = idx / D_;
    int i = idx - n * D_;
    double expo = (double)(2 * (i / 2)) / (double)D_;
    double ang  = (double)n / pow(10000.0, expo);
    pose[idx] = (float)((i & 1) ? cos(ang) : sin(ang));
}

// ------------------------- weight prep -------------------------
// A-side: WT[n][k] (k padded to 128): k<100 = W[k][n], k==100 = bias[n], else 0.
__global__ __launch_bounds__(256) void k_prep_a(const float* __restrict__ W,
        const float* __restrict__ bias, f16* __restrict__ WT, int N, int NP){
    int idx = blockIdx.x * 256 + threadIdx.x;
    if (idx >= NP * 128) return;
    int n = idx >> 7, k = idx & 127;
    float v = 0.f;
    if (n < N){
        if (k < 100) v = W[(size_t)k * N + n];
        else if (k == 100) v = bias[n];
    }
    WT[idx] = (f16)v;
}

// B-side: WT[d][f] (d padded to 112): d<100 = W[f*100+d], else 0.
__global__ __launch_bounds__(256) void k_prep_b(const float* __restrict__ W,
        f16* __restrict__ WT, int F, int lg2F){
    int idx = blockIdx.x * 256 + threadIdx.x;
    if (idx >= 112 * F) return;
    int f = idx & (F - 1);
    int d = idx >> lg2F;
    WT[(size_t)d * F + f] = (d < 100) ? (f16)W[(size_t)f * 100 + d] : (f16)0.f;
}

// ------------------------- MFMA GEMM: out = x_aug @ WT^T -------------------------
// x (25600,100) f32; WT [NP][128] f16 prepped (k=100 holds bias).
// 128 thr = 2 waves x (RT*16) rows. grid.y covers N in chunks of 112.
// wls: 112 rows x 256B, swizzle byte ^= (row&7)<<4.
template<int RT, bool F16OUT>
__global__ __launch_bounds__(128) void k_gemm16(
        const float* __restrict__ x, const f16* __restrict__ WT,
        float* __restrict__ outf, f16* __restrict__ outh, int N){
    __shared__ f16 wls[112 * 128];   // 28KB
    int tid = threadIdx.x;
    int wv = tid >> 6, lane = tid & 63;
    int l15 = lane & 15, lg = lane >> 4;
    int row0 = blockIdx.x * (RT * 32) + wv * (RT * 16);
    int c0 = blockIdx.y * 112;

    // stage WT chunk: 112 rows x 16 slots of 16B
    for (int c = tid; c < 1792; c += 128){
        int n = c >> 4, slot = c & 15;
        uint4 v = *(const uint4*)(WT + (size_t)(c0 + n) * 128 + slot * 8);
        *(uint4*)((char*)wls + n * 256 + ((slot * 16) ^ ((n & 7) << 4))) = v;
    }

    // x fragments in registers (k-augmented: elem k=100 -> 1.0)
    f16x8 xf[RT][4];
    #pragma unroll
    for (int rt = 0; rt < RT; ++rt){
        const float* xr = x + (size_t)(row0 + rt * 16 + l15) * 100;
        #pragma unroll
        for (int ks = 0; ks < 3; ++ks){
            int k0 = ks * 32 + lg * 8;
            float4 a = *(const float4*)(xr + k0);
            float4 b = *(const float4*)(xr + k0 + 4);
            f16 t[8] = {(f16)a.x,(f16)a.y,(f16)a.z,(f16)a.w,(f16)b.x,(f16)b.y,(f16)b.z,(f16)b.w};
            xf[rt][ks] = *(const f16x8*)t;
        }
        if (lg == 0){
            float4 a = *(const float4*)(xr + 96);
            f16 t[8] = {(f16)a.x,(f16)a.y,(f16)a.z,(f16)a.w,(f16)1.f,(f16)0.f,(f16)0.f,(f16)0.f};
            xf[rt][3] = *(const f16x8*)t;
        } else {
            f16 t[8] = {(f16)0.f,(f16)0.f,(f16)0.f,(f16)0.f,(f16)0.f,(f16)0.f,(f16)0.f,(f16)0.f};
            xf[rt][3] = *(const f16x8*)t;
        }
    }
    __syncthreads();

    f32x4 acc[RT][7];
    #pragma unroll
    for (int rt = 0; rt < RT; ++rt)
        #pragma unroll
        for (int ct = 0; ct < 7; ++ct) acc[rt][ct] = (f32x4)0.f;

    #pragma unroll
    for (int ks = 0; ks < 4; ++ks){
        #pragma unroll
        for (int ct = 0; ct < 7; ++ct){
            int n = ct * 16 + l15;
            f16x8 a = *(const f16x8*)((char*)wls + n * 256 + ((ks * 64 + lg * 16) ^ ((n & 7) << 4)));
            #pragma unroll
            for (int rt = 0; rt < RT; ++rt)
                acc[rt][ct] = __builtin_amdgcn_mfma_f32_16x16x32_f16(a, xf[rt][ks], acc[rt][ct], 0, 0, 0);
        }
    }

    // epilogue: lane holds 4 consecutive out-cols (col = c0 + ct*16 + lg*4 + reg)
    #pragma unroll
    for (int rt = 0; rt < RT; ++rt){
        int r = row0 + rt * 16 + l15;
        #pragma unroll
        for (int ct = 0; ct < 7; ++ct){
            int col = c0 + ct * 16 + lg * 4;
            if (col + 4 <= N){
                if (F16OUT){
                    f16 t[4] = {(f16)acc[rt][ct][0], (f16)acc[rt][ct][1],
                                (f16)acc[rt][ct][2], (f16)acc[rt][ct][3]};
                    *(uint2*)(outh + (size_t)r * N + col) = *(const uint2*)t;
                } else {
                    *(f32x4*)(outf + (size_t)r * N + col) = acc[rt][ct];
                }
            }
        }
    }
}

// ------------------------- fused FFN (split-F x4, partial outputs) -------------------------
// x (25600,100) f32; WaT [F][128] f16 (k-aug with bias); WbT [112][F] f16.
// grid (200, 4): 128 rows/block (2 waves x 64), F-quarter per blockIdx.y.
// P = Pbase + y*2560000 gets the partial out (f32). Chunk = 64 f.
template<int ACT>   // 0 relu, 1 leaky 0.01
__global__ __launch_bounds__(128) void k_ffn2(
        const float* __restrict__ x, const f16* __restrict__ WaT,
        const f16* __restrict__ WbT, float* __restrict__ Pbase, int F){
    __shared__ f16 waTs[64 * 128];    // 16KB: 64 f-rows x 256B
    __shared__ f16 wbTs[112 * 64];    // 14KB: 112 d-rows x 128B
    __shared__ f16 hs[2 * 64 * 64];   // 16KB: per-wave 64 xrows x 128B
    int tid = threadIdx.x;
    int wv = tid >> 6, lane = tid & 63;
    int l15 = lane & 15, lg = lane >> 4;
    int row0 = blockIdx.x * 128 + wv * 64;
    int Fq = F >> 2;
    float* P = Pbase + (size_t)blockIdx.y * 2560000;

    // x fragments in registers (k-augmented)
    f16x8 xf[4][4];
    #pragma unroll
    for (int rt = 0; rt < 4; ++rt){
        const float* xr = x + (size_t)(row0 + rt * 16 + l15) * 100;
        #pragma unroll
        for (int ks = 0; ks < 3; ++ks){
            int k0 = ks * 32 + lg * 8;
            float4 a = *(const float4*)(xr + k0);
            float4 b = *(const float4*)(xr + k0 + 4);
            f16 t[8] = {(f16)a.x,(f16)a.y,(f16)a.z,(f16)a.w,(f16)b.x,(f16)b.y,(f16)b.z,(f16)b.w};
            xf[rt][ks] = *(const f16x8*)t;
        }
        if (lg == 0){
            float4 a = *(const float4*)(xr + 96);
            f16 t[8] = {(f16)a.x,(f16)a.y,(f16)a.z,(f16)a.w,(f16)1.f,(f16)0.f,(f16)0.f,(f16)0.f};
            xf[rt][3] = *(const f16x8*)t;
        } else {
            f16 t[8] = {(f16)0.f,(f16)0.f,(f16)0.f,(f16)0.f,(f16)0.f,(f16)0.f,(f16)0.f,(f16)0.f};
            xf[rt][3] = *(const f16x8*)t;
        }
    }

    f32x4 acc[4][7];
    #pragma unroll
    for (int rt = 0; rt < 4; ++rt)
        #pragma unroll
        for (int ct = 0; ct < 7; ++ct) acc[rt][ct] = (f32x4)0.f;

    int nch = Fq >> 6;
    for (int ch = 0; ch < nch; ++ch){
        int f0 = blockIdx.y * Fq + ch * 64;
        __syncthreads();   // previous chunk fully consumed
        // stage WaT chunk: 64 f-rows x 16 slots
        for (int c = tid; c < 1024; c += 128){
            int f = c >> 4, slot = c & 15;
            uint4 v = *(const uint4*)(WaT + (size_t)(f0 + f) * 128 + slot * 8);
            *(uint4*)((char*)waTs + f * 256 + ((slot * 16) ^ ((f & 7) << 4))) = v;
        }
        // stage WbT chunk: 112 d-rows x 8 slots
        for (int c = tid; c < 896; c += 128){
            int d = c >> 3, s = c & 7;
            uint4 v = *(const uint4*)(WbT + (size_t)d * F + f0 + s * 8);
            *(uint4*)((char*)wbTs + d * 128 + ((s * 16) ^ ((d & 7) << 4))) = v;
        }
        __syncthreads();

        // phase 1: H(16f x 64 rows) per ctp; act; pack to hs
        #pragma unroll
        for (int ctp = 0; ctp < 4; ++ctp){
            f32x4 h[4];
            #pragma unroll
            for (int rt = 0; rt < 4; ++rt) h[rt] = (f32x4)0.f;
            #pragma unroll
            for (int ks = 0; ks < 4; ++ks){
                int fl = ctp * 16 + l15;
                f16x8 a = *(const f16x8*)((char*)waTs + fl * 256 + ((ks * 64 + lg * 16) ^ ((fl & 7) << 4)));
                #pragma unroll
                for (int rt = 0; rt < 4; ++rt)
                    h[rt] = __builtin_amdgcn_mfma_f32_16x16x32_f16(a, xf[rt][ks], h[rt], 0, 0, 0);
            }
            // lane holds f = ctp*16 + lg*4 + reg for xrow rt*16+l15
            #pragma unroll
            for (int rt = 0; rt < 4; ++rt){
                f16 t[4];
                #pragma unroll
                for (int reg = 0; reg < 4; ++reg){
                    float v = h[rt][reg];
                    v = (v > 0.f) ? v : (ACT ? 0.01f * v : 0.f);
                    t[reg] = (f16)v;
                }
                int xr = rt * 16 + l15;
                *(uint2*)((char*)hs + wv * 8192 + xr * 128 + ((ctp * 32 + lg * 8) ^ ((xr & 7) << 4))) = *(const uint2*)t;
            }
        }
        // phase 2: acc += WbT_chunk . H   (H as B-operand)
        #pragma unroll
        for (int ks2 = 0; ks2 < 2; ++ks2){
            f16x8 bf[4];
            #pragma unroll
            for (int rt = 0; rt < 4; ++rt){
                int xr = rt * 16 + l15;
                bf[rt] = *(const f16x8*)((char*)hs + wv * 8192 + xr * 128 + ((ks2 * 64 + lg * 16) ^ ((xr & 7) << 4)));
            }
            #pragma unroll
            for (int ct = 0; ct < 7; ++ct){
                int d = ct * 16 + l15;
                f16x8 a2 = *(const f16x8*)((char*)wbTs + d * 128 + ((ks2 * 64 + lg * 16) ^ ((d & 7) << 4)));
                #pragma unroll
                for (int rt = 0; rt < 4; ++rt)
                    acc[rt][ct] = __builtin_amdgcn_mfma_f32_16x16x32_f16(a2, bf[rt], acc[rt][ct], 0, 0, 0);
            }
        }
    }

    // epilogue: partial out (f32), 4 consecutive cols per lane
    #pragma unroll
    for (int rt = 0; rt < 4; ++rt){
        int r = row0 + rt * 16 + l15;
        #pragma unroll
        for (int ct = 0; ct < 7; ++ct){
            int col = ct * 16 + lg * 4;
            if (col < 100)
                *(f32x4*)(P + (size_t)r * 100 + col) = acc[rt][ct];
        }
    }
}

// ------------------------- attention (per b,head), f16 qkv -------------------------
__global__ __launch_bounds__(128) void k_attn(const f16* __restrict__ qkv,
                                              float* __restrict__ o){
    int b = blockIdx.x >> 2;
    int h = blockIdx.x & 3;
    __shared__ float ks[100][26];
    __shared__ float vs[100][26];
    for (int i = threadIdx.x; i < 2500; i += 128){
        int n = i / 25, d = i - n * 25;
        const f16* base = qkv + (size_t)(b * 100 + n) * 300 + h * 25 + d;
        ks[n][d] = (float)base[100];
        vs[n][d] = (float)base[200];
    }
    __syncthreads();
    int n = threadIdx.x;
    if (n < 100){
        float q[25];
        const f16* qb = qkv + (size_t)(b * 100 + n) * 300 + h * 25;
        #pragma unroll
        for (int d = 0; d < 25; ++d) q[d] = (float)qb[d];
        float m = -FLT_MAX, l = 0.f, acc[25];
        #pragma unroll
        for (int d = 0; d < 25; ++d) acc[d] = 0.f;
        for (int c = 0; c < 100; ++c){
            float s = 0.f;
            #pragma unroll
            for (int d = 0; d < 25; ++d) s += q[d] * ks[c][d];
            s *= 0.2f;
            if (s <= m){
                float p = expf(s - m);
                l += p;
                #pragma unroll
                for (int d = 0; d < 25; ++d) acc[d] += p * vs[c][d];
            } else {
                float sc = expf(m - s);
                l = l * sc + 1.f;
                #pragma unroll
                for (int d = 0; d < 25; ++d) acc[d] = acc[d] * sc + vs[c][d];
                m = s;
            }
        }
        float inv = 1.f / l;
        float* ob = o + (size_t)(b * 100 + n) * 100 + h * 25;
        #pragma unroll
        for (int d = 0; d < 25; ++d) ob[d] = acc[d] * inv;
    }
}

// ------------------------- fused add + LayerNorm (residual + up to 4 partials) -------------------------
__global__ __launch_bounds__(256) void k_add_ln(
        const float* __restrict__ xa, const float* __restrict__ p1,
        const float* __restrict__ p2, const float* __restrict__ p3,
        const float* __restrict__ p4, const float* __restrict__ bias,
        const float* __restrict__ g, const float* __restrict__ bt,
        float* __restrict__ out){
    int row  = blockIdx.x * 4 + (threadIdx.x >> 6);
    int lane = threadIdx.x & 63;
    size_t off = (size_t)row * 100;
    int e1 = lane + 64;
    bool has1 = e1 < 100;
    float v0 = xa[off + lane] + p1[off + lane];
    float v1 = has1 ? (xa[off + e1] + p1[off + e1]) : 0.f;
    if (p2){
        v0 += p2[off + lane] + p3[off + lane] + p4[off + lane];
        if (has1) v1 += p2[off + e1] + p3[off + e1] + p4[off + e1];
    }
    if (bias){
        v0 += bias[lane];
        if (has1) v1 += bias[e1];
    }
    float s = v0 + v1;
    #pragma unroll
    for (int m = 32; m >= 1; m >>= 1) s += __shfl_xor(s, m, 64);
    float mean = s / 100.f;
    float d0 = v0 - mean;
    float d1 = has1 ? (v1 - mean) : 0.f;
    float s2 = d0 * d0 + d1 * d1;
    #pragma unroll
    for (int m = 32; m >= 1; m >>= 1) s2 += __shfl_xor(s2, m, 64);
    float rstd = 1.f / sqrtf(s2 / 100.f + 1e-5f);
    float* po = out + off;
    po[lane] = d0 * rstd * g[lane] + bt[lane];
    if (has1) po[e1] = d1 * rstd * g[e1] + bt[e1];
}

// ------------------------- subnet means + cosine cost -------------------------
__global__ __launch_bounds__(256) void k_subnet_cost(const float* __restrict__ feat,
                                                     float* __restrict__ cost){
    int b = blockIdx.x;
    __shared__ float fs[100][101];
    __shared__ float sf[7][101];
    __shared__ float nf[100];
    __shared__ float ns[7];
    int tid = threadIdx.x;
    for (int idx = tid; idx < 10000; idx += 256){
        int n = idx / 100, d = idx - n * 100;
        fs[n][d] = feat[(size_t)(b * 100 + n) * 100 + d];
    }
    __syncthreads();
    const float cnt[7] = {17.f, 14.f, 15.f, 12.f, 5.f, 13.f, 24.f};
    for (int idx = tid; idx < 700; idx += 256){
        int k = idx / 100, d = idx - k * 100;
        float s = 0.f;
        for (int n = 0; n < 100; ++n) if (d_node2k[n] == k) s += fs[n][d];
        sf[k][d] = s / (cnt[k] + 1e-6f);
    }
    __syncthreads();
    if (tid < 100){
        float s = 0.f;
        for (int d = 0; d < 100; ++d) s += fs[tid][d] * fs[tid][d];
        float nv = sqrtf(s);
        nf[tid] = nv > 1e-12f ? nv : 1e-12f;
    }
    if (tid >= 128 && tid < 135){
        int k = tid - 128;
        float s = 0.f;
        for (int d = 0; d < 100; ++d) s += sf[k][d] * sf[k][d];
        float nv = sqrtf(s);
        ns[k] = nv > 1e-12f ? nv : 1e-12f;
    }
    __syncthreads();
    for (int idx = tid; idx < 700; idx += 256){
        int n = idx / 7, k = idx - n * 7;
        float s = 0.f;
        for (int d = 0; d < 100; ++d) s += fs[n][d] * sf[k][d];
        cost[(size_t)b * 700 + n * 7 + k] = s / (nf[n] * ns[k]);
    }
}

// ------------------------- sinkhorn (f64, per image, cold start) -------------------------
__global__ __launch_bounds__(128) void k_sinkhorn(const float* __restrict__ cost,
        float* __restrict__ qplan, float* __restrict__ qual,
        const int* __restrict__ ep){
    int b   = blockIdx.x;
    int tid = threadIdx.x;
    __shared__ double Qm[100][8];
    __shared__ double av[100];
    __shared__ double bv[8];
    __shared__ double b2v[8];
    __shared__ int s_stop;
    double rho = get_rho(ep[0]);
    const double prior[7] = {17.0/100.0, 14.0/100.0, 15.0/100.0, 12.0/100.0,
                             5.0/100.0, 13.0/100.0, 24.0/100.0};
    if (tid < 100){
        double c[7]; double mx = -1e300;
        for (int k = 0; k < 7; ++k){
            c[k] = (double)cost[(size_t)b * 700 + tid * 7 + k];
            if (c[k] > mx) mx = c[k];
        }
        double se = 0.0;
        for (int k = 0; k < 7; ++k) se += exp(c[k] - mx);
        double lse = mx + log(se);
        for (int k = 0; k < 7; ++k) Qm[tid][k] = exp(-((lse - c[k]) / 0.1));
        Qm[tid][7] = 1.0;
    }
    if (tid < 8) bv[tid] = 1.0 / 8.0;
    if (tid == 0) s_stop = 0;
    __syncthreads();
    const double fi = 1.0 / 1.1;
    int j = tid >> 4, l16 = tid & 15;
    double Pbj = (j < 7) ? rho * prior[j] : (1.0 - rho);
    for (int it = 0; it < 50; ++it){
        if (tid < 100){
            double s = 0.0;
            #pragma unroll
            for (int k = 0; k < 8; ++k) s += Qm[tid][k] * bv[k];
            av[tid] = 0.01 / s;
        }
        __syncthreads();
        double p = 0.0;
        for (int n = l16; n < 100; n += 16) p += Qm[n][j] * av[n];
        p += __shfl_xor(p, 8, 16);
        p += __shfl_xor(p, 4, 16);
        p += __shfl_xor(p, 2, 16);
        p += __shfl_xor(p, 1, 16);
        if (l16 == 0){
            double nb = Pbj / p;
            if (j < 7) nb = pow(nb, fi);
            b2v[j] = nb;
        }
        __syncthreads();
        if (tid == 0){
            double e2 = 0.0;
            #pragma unroll
            for (int k = 0; k < 8; ++k){
                double d = b2v[k] - bv[k];
                e2 += d * d;
                bv[k] = b2v[k];
            }
            s_stop = (e2 <= 1e-12) ? 1 : 0;
        }
        __syncthreads();
        if (s_stop) break;
    }
    if (tid < 100){
        float q = 0.f;
        for (int k = 0; k < 7; ++k){
            double pl = 100.0 * av[tid] * Qm[tid][k] * bv[k];
            float pf = (float)pl;
            qplan[(size_t)b * 700 + tid * 7 + k] = pf;
            q += pf;
        }
        qual[(size_t)b * 100 + tid] = q;
    }
}

// ------------------------- selection -------------------------
__global__ __launch_bounds__(128) void k_select(const float* __restrict__ qual,
        const float* __restrict__ qplan, const float* __restrict__ randK,
        const int* __restrict__ ep, float* __restrict__ maskb){
    int b   = blockIdx.x;
    int tid = threadIdx.x;
    __shared__ float qs[100];
    __shared__ float sorted_s[100];
    __shared__ float noise_s[100];
    __shared__ float thr_f;
    if (tid < 100) qs[tid] = qual[(size_t)b * 100 + tid];
    __syncthreads();
    if (tid < 100){
        float q = qs[tid];
        int cl = 0, ce = 0;
        for (int m = 0; m < 100; ++m){ cl += (qs[m] < q); ce += (qs[m] == q); }
        for (int r2 = cl; r2 < cl + ce; ++r2) sorted_s[r2] = q;
    }
    __syncthreads();
    if (tid == 0){
        double rho = get_rho(ep[0]);
        double pos = (1.0 - rho) * 99.0;
        int lo = (int)floor(pos);
        if (lo > 98) lo = 98; if (lo < 0) lo = 0;
        double fr = pos - (double)lo;
        double thr = (double)sorted_s[lo] + ((double)sorted_s[lo + 1] - (double)sorted_s[lo]) * fr;
        thr_f = (float)thr;
    }
    __syncthreads();
    if (tid < 100){
        float nz = 0.f;
        if (!(qs[tid] < thr_f)){
            for (int k = 0; k < 7; ++k)
                nz += qplan[(size_t)b * 700 + tid * 7 + k] * randK[b * 7 + k];
        }
        noise_s[tid] = nz;
    }
    __syncthreads();
    if (tid < 100){
        float nz = noise_s[tid];
        int rk = 0;
        for (int m = 0; m < 100; ++m){
            rk += (noise_s[m] < nz);
            rk += ((noise_s[m] == nz) && (m < tid));
        }
        maskb[(size_t)b * 100 + tid] = (rk >= 90) ? 1.f : 0.f;
    }
}

// ------------------------- build decoder input -------------------------
__global__ void k_build_x(const float* __restrict__ imgs, const float* __restrict__ mtok,
        const float* __restrict__ maskb, const float* __restrict__ pose,
        float* __restrict__ x){
    int idx = blockIdx.x * 256 + threadIdx.x;
    if (idx >= B_ * N_ * D_) return;
    int d  = idx % 100;
    int bn = idx / 100;
    int n  = bn % 100;
    float v = (maskb[bn] == 0.f) ? imgs[idx] : mtok[d];
    x[idx] = v + pose[n * 100 + d];
}

// ------------------------- loss: two-stage reduction -------------------------
__global__ __launch_bounds__(256) void k_loss(const float* __restrict__ p1,
        const float* __restrict__ p2, const float* __restrict__ p3,
        const float* __restrict__ p4, const float* __restrict__ pb2,
        const float* __restrict__ imgs, const float* __restrict__ maskb,
        double* __restrict__ partial){
    int wv   = threadIdx.x >> 6;
    int row  = blockIdx.x * 4 + wv;
    int lane = threadIdx.x & 63;
    size_t off = (size_t)row * 100;
    float d0 = p1[off+lane] + p2[off+lane] + p3[off+lane] + p4[off+lane] + pb2[lane] - imgs[off+lane];
    float s = d0 * d0;
    int e1 = lane + 64;
    if (e1 < 100){
        float d1 = p1[off+e1] + p2[off+e1] + p3[off+e1] + p4[off+e1] + pb2[e1] - imgs[off+e1];
        s += d1 * d1;
    }
    #pragma unroll
    for (int m = 32; m >= 1; m >>= 1) s += __shfl_xor(s, m, 64);
    __shared__ float ls[4], lc[4];
    if (lane == 0){
        float mk = maskb[row];
        ls[wv] = (s / 100.f) * mk;
        lc[wv] = mk;
    }
    __syncthreads();
    if (threadIdx.x == 0){
        partial[2 * blockIdx.x]     = (double)(ls[0] + ls[1] + ls[2] + ls[3]);
        partial[2 * blockIdx.x + 1] = (double)(lc[0] + lc[1] + lc[2] + lc[3]);
    }
}

__global__ __launch_bounds__(256) void k_final(const double* __restrict__ partial,
                                               float* __restrict__ out){
    int tid = threadIdx.x;
    double s = 0.0, c = 0.0;
    for (int i = tid; i < 6400; i += 256){
        s += partial[2 * i];
        c += partial[2 * i + 1];
    }
    #pragma unroll
    for (int m = 32; m >= 1; m >>= 1){
        s += __shfl_xor(s, m, 64);
        c += __shfl_xor(c, m, 64);
    }
    __shared__ double ss[4], cs[4];
    if ((tid & 63) == 0){ ss[tid >> 6] = s; cs[tid >> 6] = c; }
    __syncthreads();
    if (tid == 0){
        double S = ss[0] + ss[1] + ss[2] + ss[3];
        double C = cs[0] + cs[1] + cs[2] + cs[3];
        out[0] = (float)(S / C);
    }
}

// ------------------------- host -------------------------
extern "C" void kernel_launch(void* const* d_in, const int* in_sizes, int n_in,
                              void* d_out, int out_size, void* d_ws, size_t ws_size,
                              hipStream_t stream){
    const float* imgs = (const float*)d_in[0];
    const float* Wqkv = (const float*)d_in[1];
    const float* bqkv = (const float*)d_in[2];
    const float* Wo   = (const float*)d_in[3];
    const float* bo   = (const float*)d_in[4];
    const float* ln1g = (const float*)d_in[5];
    const float* ln1b = (const float*)d_in[6];
    const float* W1   = (const float*)d_in[7];
    const float* b1   = (const float*)d_in[8];
    const float* W2   = (const float*)d_in[9];
    const float* b2   = (const float*)d_in[10];
    const float* ln2g = (const float*)d_in[11];
    const float* ln2b = (const float*)d_in[12];
    const float* mtok = (const float*)d_in[13];
    const float* pW1  = (const float*)d_in[14];
    const float* pb1  = (const float*)d_in[15];
    const float* pW2  = (const float*)d_in[16];
    const float* pb2  = (const float*)d_in[17];
    const float* rndK = (const float*)d_in[18];
    const int*   epoch = (const int*)d_in[19];

    float* ws   = (float*)d_ws;
    float* Xb   = ws;                         // 2,560,000
    float* P1   = Xb + 2560000;
    float* P2   = P1 + 2560000;
    float* P3   = P2 + 2560000;               // overlaid by QKVh (disjoint in time)
    float* P4   = P3 + 2560000;
    f16*   QKVh = (f16*)P3;                   // 7,680,000 f16 = 3,840,000 f32 span (P3 + part of P4)
    float* COSTb  = P4 + 2560000;             // 12,800,000
    float* QPLANb = COSTb + 179200;
    float* QUALb  = QPLANb + 179200;
    float* WARENA = QUALb + 25600;            // 13,184,000
    f16* wh = (f16*)WARENA;
    f16* WqkvT0 = wh;               wh += 43008;    // 336*128
    f16* WqkvT1 = wh;               wh += 43008;
    f16* WoT0   = wh;               wh += 14336;    // 112*128
    f16* WoT1   = wh;               wh += 14336;
    f16* W1T0   = wh;               wh += 262144;   // 2048*128
    f16* W1T1   = wh;               wh += 262144;
    f16* W2T0   = wh;               wh += 229376;   // 112*2048
    f16* W2T1   = wh;               wh += 229376;
    f16* PW1T   = wh;               wh += 131072;   // 1024*128
    f16* PW2T   = wh;               wh += 114688;   // 112*1024
    float* tail = WARENA + 671744;
    float* MASKb = tail;            tail += 25600;
    float* POSEb = tail;            tail += 10000;
    double* LOSSP = (double*)tail;  // 6400*2 doubles

    // one-time weight prep
    k_prep_a<<<168,  256, 0, stream>>>(Wqkv,          bqkv,       WqkvT0, 300, 336);
    k_prep_a<<<168,  256, 0, stream>>>(Wqkv + 30000,  bqkv + 300, WqkvT1, 300, 336);
    k_prep_a<<<56,   256, 0, stream>>>(Wo,            bo,         WoT0,   100, 112);
    k_prep_a<<<56,   256, 0, stream>>>(Wo + 10000,    bo + 100,   WoT1,   100, 112);
    k_prep_a<<<1024, 256, 0, stream>>>(W1,            b1,         W1T0,  2048, 2048);
    k_prep_a<<<1024, 256, 0, stream>>>(W1 + 204800,   b1 + 2048,  W1T1,  2048, 2048);
    k_prep_b<<<896,  256, 0, stream>>>(W2,          W2T0, 2048, 11);
    k_prep_b<<<896,  256, 0, stream>>>(W2 + 204800, W2T1, 2048, 11);
    k_prep_a<<<512,  256, 0, stream>>>(pW1, pb1, PW1T, 1024, 1024);
    k_prep_b<<<448,  256, 0, stream>>>(pW2, PW2T, 1024, 10);
    k_pos_embed<<<79, 128, 0, stream>>>(POSEb);

    auto layer = [&](const float* xi, float* xo, int l){
        k_gemm16<2, true><<<dim3(400, 3), 128, 0, stream>>>(
            xi, l ? WqkvT1 : WqkvT0, nullptr, QKVh, 300);
        k_attn<<<1024, 128, 0, stream>>>(QKVh, P1);
        k_gemm16<2, false><<<dim3(400, 1), 128, 0, stream>>>(
            P1, l ? WoT1 : WoT0, P2, nullptr, 100);
        k_add_ln<<<6400, 256, 0, stream>>>(xi, P2, nullptr, nullptr, nullptr,
            nullptr, ln1g + l * 100, ln1b + l * 100, xo);
        k_ffn2<0><<<dim3(200, 4), 128, 0, stream>>>(
            xo, l ? W1T1 : W1T0, l ? W2T1 : W2T0, P1, 2048);
        k_add_ln<<<6400, 256, 0, stream>>>(xo, P1, P2, P3, P4, b2 + l * 100,
            ln2g + l * 100, ln2b + l * 100, xo);
    };

    // encoder on stop_gradient(imgs) -> feat in Xb
    layer(imgs, Xb, 0);
    layer(Xb, Xb, 1);

    k_subnet_cost<<<256, 256, 0, stream>>>(Xb, COSTb);
    k_sinkhorn<<<256, 128, 0, stream>>>(COSTb, QPLANb, QUALb, epoch);
    k_select<<<256, 128, 0, stream>>>(QUALb, QPLANb, rndK, epoch, MASKb);

    // decoder input overwrites Xb
    k_build_x<<<10000, 256, 0, stream>>>(imgs, mtok, MASKb, POSEb, Xb);

    layer(Xb, Xb, 0);
    layer(Xb, Xb, 1);

    // predictor: leaky_relu(x@pW1+pb1)@pW2 -> partials P1..P4 (pb2 added in loss)
    k_ffn2<1><<<dim3(200, 4), 128, 0, stream>>>(Xb, PW1T, PW2T, P1, 1024);

    k_loss<<<6400, 256, 0, stream>>>(P1, P2, P3, P4, pb2, imgs, MASKb, LOSSP);
    k_final<<<1, 256, 0, stream>>>(LOSSP, (float*)d_out);
}